// Round 11
// baseline (122.435 us; speedup 1.0000x reference)
//
#include <hip/hip_runtime.h>

// DepthDeformConv — round 11: r8's proven bf16 body, restructured for
// occupancy.
//   r9/r10 fp16 failed with identical wrong-output signature (1.703125 !=
//   zero-output 1.3515625 -> deterministic wrong values in the fp16 path);
//   and r7->r8 scaling shows the main kernel is VMEM-request-bound, not
//   VALU-bound, so fp16's VALU savings were worthless anyway. Dropped.
//   This round: corner gathers are already at the minimum instruction
//   count; the binding limit is grid concurrency (r8: 512 blocks = 2/CU =
//   16 waves/CU). Now 256-thr blocks (4 waves x 16 px), grid 1024, LDS
//   tap-window 24 KB (3 taps, 3 phases) -> 6 blocks/CU = 24 waves/CU.

typedef __attribute__((ext_vector_type(8))) short bf16x8;
typedef __attribute__((ext_vector_type(4))) float f32x4;
typedef __attribute__((ext_vector_type(4))) unsigned int u32x4;

#define HH 128
#define WW 128
#define CC 64
#define OO 64
#define HW (128 * 128)

__device__ __forceinline__ unsigned f32_to_bf16_rne(float f) {
    unsigned u = __float_as_uint(f);
    return (u + 0x7FFFu + ((u >> 16) & 1u)) >> 16;
}

// ---------------- kernel 1a: NCHW f32 -> NHWC bf16 ----------------
__global__ __launch_bounds__(256)
void prep_nhwc(const float* __restrict__ input,
               unsigned short* __restrict__ nhwc)
{
    // one block per (b, y, x-quarter): 64c x 32x tile via LDS
    __shared__ unsigned tile[64][33];
    const int tid = threadIdx.x;
    const int blk = blockIdx.x;
    const int b  = blk >> 9;
    const int y  = (blk >> 2) & 127;
    const int xbase = (blk & 3) * 32;
    #pragma unroll
    for (int it = 0; it < 8; ++it) {
        int flat = it * 256 + tid;          // 0..2047
        int c = flat >> 5, x = flat & 31;
        float v = input[((b * 64 + c) * 128 + y) * 128 + xbase + x];
        tile[c][x] = f32_to_bf16_rne(v);
    }
    __syncthreads();
    {
        int x = tid >> 3, cg = tid & 7;     // 32x * 8 channel-groups
        unsigned r0 = tile[cg * 8 + 0][x], r1 = tile[cg * 8 + 1][x];
        unsigned r2 = tile[cg * 8 + 2][x], r3 = tile[cg * 8 + 3][x];
        unsigned r4 = tile[cg * 8 + 4][x], r5 = tile[cg * 8 + 5][x];
        unsigned r6 = tile[cg * 8 + 6][x], r7 = tile[cg * 8 + 7][x];
        u32x4 pk;
        pk[0] = r0 | (r1 << 16); pk[1] = r2 | (r3 << 16);
        pk[2] = r4 | (r5 << 16); pk[3] = r6 | (r7 << 16);
        *(u32x4*)(nhwc + ((size_t)((b * 128 + y) * 128 + xbase + x)) * 64 + cg * 8) = pk;
    }
}

// ---------------- kernel 1b: weight -> K8-major bf16 ----------------
// wT2 as uint4[4608]: entry d=(kt*8+c8)*64+o holds bf16 weights for
// channels c8*8..c8*8+7 of (o, tap kt).
__global__ __launch_bounds__(256)
void prep_w(const float* __restrict__ weight,
            unsigned short* __restrict__ wT2)
{
    const int d  = blockIdx.x * 256 + threadIdx.x;  // 0..4607
    const int o  = d & 63;
    const int k8 = d >> 6;                          // 0..71
    const int kt = k8 >> 3;
    const int c8 = k8 & 7;
    u32x4 pk;
    #pragma unroll
    for (int jj = 0; jj < 4; ++jj) {
        unsigned lo = f32_to_bf16_rne(weight[o * 576 + (c8 * 8 + 2 * jj)     * 9 + kt]);
        unsigned hi = f32_to_bf16_rne(weight[o * 576 + (c8 * 8 + 2 * jj + 1) * 9 + kt]);
        pk[jj] = lo | (hi << 16);
    }
    *(u32x4*)(wT2 + (size_t)d * 8) = pk;
}

// ---------------- kernel 2: fused sample + MFMA ----------------
__global__ __launch_bounds__(256)
void ddc_main(const unsigned short* __restrict__ nhwc,
              const unsigned short* __restrict__ wT2,
              const float* __restrict__ offset,
              const float* __restrict__ mask,
              const float* __restrict__ bias,
              float* __restrict__ out)
{
    __shared__ u32x4 wbuf[1536];           // 24 KB: 3-tap weight window

    const int blk  = blockIdx.x;           // 1024 = 4b * 128h * 2 halves
    const int b    = blk >> 8;
    const int h    = (blk >> 1) & 127;
    const int half = blk & 1;
    const int tid  = threadIdx.x;
    const int wave = tid >> 6;             // 4 pixel groups
    const int lane = tid & 63;
    const int l15  = lane & 15;            // pixel within group / o-row (A)
    const int kq   = lane >> 4;            // k-chunk quad (0..3)
    const int wpix = half * 64 + wave * 16 + l15;   // w coordinate

    f32x4 acc[4];
    #pragma unroll
    for (int mt = 0; mt < 4; ++mt) acc[mt] = (f32x4){0.f, 0.f, 0.f, 0.f};

    const unsigned short* nb = nhwc + (size_t)b * HW * CC;
    const u32x4* wsrc = (const u32x4*)wT2;

    auto do_tap = [&](int kt, int ktl) {
        // ---- stencil for (pixel, tap) ----
        const float oy = offset[((b * 18 + 2 * kt)     * 128 + h) * 128 + wpix];
        const float ox = offset[((b * 18 + 2 * kt + 1) * 128 + h) * 128 + wpix];
        const float m  = mask  [((b * 9  + kt)         * 128 + h) * 128 + wpix];
        const float py = (float)(h - 1 + kt / 3) + oy;
        const float px = (float)(wpix - 1 + kt % 3) + ox;
        const float y0f = floorf(py), x0f = floorf(px);
        const int y0 = (int)y0f, x0 = (int)x0f;
        const float wy = py - y0f, wx = px - x0f;
        const int y1 = y0 + 1, x1 = x0 + 1;
        const bool vy0 = (y0 >= 0) & (y0 < HH);
        const bool vy1 = (y1 >= 0) & (y1 < HH);
        const bool vx0 = (x0 >= 0) & (x0 < WW);
        const bool vx1 = (x1 >= 0) & (x1 < WW);
        const int y0c = min(max(y0, 0), HH - 1), y1c = min(max(y1, 0), HH - 1);
        const int x0c = min(max(x0, 0), WW - 1), x1c = min(max(x1, 0), WW - 1);
        const float wy1 = 1.f - wy, wx1 = 1.f - wx;
        const float c00 = (vy0 && vx0) ? wy1 * wx1 * m : 0.f;
        const float c01 = (vy0 && vx1) ? wy1 * wx  * m : 0.f;
        const float c10 = (vy1 && vx0) ? wy  * wx1 * m : 0.f;
        const float c11 = (vy1 && vx1) ? wy  * wx  * m : 0.f;

        #pragma unroll
        for (int ks = 0; ks < 2; ++ks) {
            const int c0 = ks * 32 + kq * 8;   // this lane's 8-channel chunk

            const u32x4 w00 = *(const u32x4*)(nb + (y0c * WW + x0c) * CC + c0);
            const u32x4 w01 = *(const u32x4*)(nb + (y0c * WW + x1c) * CC + c0);
            const u32x4 w10 = *(const u32x4*)(nb + (y1c * WW + x0c) * CC + c0);
            const u32x4 w11 = *(const u32x4*)(nb + (y1c * WW + x1c) * CC + c0);

            u32x4 pk;
            #pragma unroll
            for (int j = 0; j < 4; ++j) {
                const float a0 = __uint_as_float(w00[j] << 16);
                const float a1 = __uint_as_float(w00[j] & 0xFFFF0000u);
                const float b0 = __uint_as_float(w01[j] << 16);
                const float b1 = __uint_as_float(w01[j] & 0xFFFF0000u);
                const float d0 = __uint_as_float(w10[j] << 16);
                const float d1 = __uint_as_float(w10[j] & 0xFFFF0000u);
                const float e0 = __uint_as_float(w11[j] << 16);
                const float e1 = __uint_as_float(w11[j] & 0xFFFF0000u);
                const float s0 = c00 * a0 + c01 * b0 + c10 * d0 + c11 * e0;
                const float s1 = c00 * a1 + c01 * b1 + c10 * d1 + c11 * e1;
                pk[j] = f32_to_bf16_rne(s0) | (f32_to_bf16_rne(s1) << 16);
            }
            const bf16x8 bfrag = __builtin_bit_cast(bf16x8, pk);

            // A-fragments from LDS
            #pragma unroll
            for (int mt = 0; mt < 4; ++mt) {
                const bf16x8 afrag = __builtin_bit_cast(bf16x8,
                    wbuf[(ktl * 8 + ks * 4 + kq) * 64 + mt * 16 + l15]);
                acc[mt] = __builtin_amdgcn_mfma_f32_16x16x32_bf16(afrag, bfrag, acc[mt], 0, 0, 0);
            }
        }
    };

    // ---- 3 phases of 3 taps (24 KB window each) ----
    #pragma unroll
    for (int ph = 0; ph < 3; ++ph) {
        if (ph) __syncthreads();           // protect previous window's readers
        #pragma unroll
        for (int i = 0; i < 6; ++i)
            wbuf[i * 256 + tid] = wsrc[ph * 1536 + i * 256 + tid];
        __syncthreads();
        #pragma unroll
        for (int t = 0; t < 3; ++t) do_tap(ph * 3 + t, t);
    }

    // ---- epilogue: C/D layout col=lane&15 (pixel), row=kq*4+reg (o) ----
    #pragma unroll
    for (int mt = 0; mt < 4; ++mt) {
        const f32x4 bv = *(const f32x4*)(bias + mt * 16 + kq * 4);
        #pragma unroll
        for (int r = 0; r < 4; ++r) {
            const int o = mt * 16 + kq * 4 + r;
            out[((b * 64 + o) * 128 + h) * 128 + wpix] = acc[mt][r] + bv[r];
        }
    }
}

extern "C" void kernel_launch(void* const* d_in, const int* in_sizes, int n_in,
                              void* d_out, int out_size, void* d_ws, size_t ws_size,
                              hipStream_t stream)
{
    const float* input  = (const float*)d_in[0];
    // d_in[1] = depth, unused by the reference
    const float* offset = (const float*)d_in[2];
    const float* mask   = (const float*)d_in[3];
    const float* weight = (const float*)d_in[4];
    const float* bias   = (const float*)d_in[5];
    float* out = (float*)d_out;

    unsigned short* nhwc = (unsigned short*)d_ws;                    // 8.39 MB
    unsigned short* wT2  = nhwc + (size_t)4 * HW * CC;               // 73728 B

    prep_nhwc<<<dim3(2048), dim3(256), 0, stream>>>(input, nhwc);
    prep_w<<<dim3(18), dim3(256), 0, stream>>>(weight, wT2);
    ddc_main<<<dim3(1024), dim3(256), 0, stream>>>(nhwc, wT2, offset, mask, bias, out);
}